// Round 13
// baseline (478.017 us; speedup 1.0000x reference)
//
#include <hip/hip_runtime.h>
#include <hip/hip_bf16.h>
#include <stdint.h>

#define BSZ 32
#define TT 128
#define NAG 16
#define NROW 4096
#define NAR 65536
#define EPSV 1e-6f

typedef __attribute__((ext_vector_type(2))) _Float16 half2v;
typedef _Float16 f16x8 __attribute__((ext_vector_type(8)));
typedef float f32x4 __attribute__((ext_vector_type(4)));

#define MFMA16(a,b,c) __builtin_amdgcn_mfma_f32_16x16x32_f16(a,b,c,0,0,0)

__device__ __forceinline__ uint32_t packh2(float a, float b) {
    union { half2v h; uint32_t u; } cu;
    cu.h.x = (_Float16)a; cu.h.y = (_Float16)b;
    return cu.u;
}

__device__ __forceinline__ float sigm(float x) { return 1.f/(1.f + __expf(-x)); }
__device__ __forceinline__ float tanh_f(float x) { return 1.f - 2.f/(__expf(2.f*x) + 1.f); }

// async 16B global->LDS; dest = wave-uniform base + lane*16 (linear)
__device__ __forceinline__ void gl_lds16(const uint32_t* g, uint32_t* lwb, int lane) {
#if __has_builtin(__builtin_amdgcn_global_load_lds)
    __builtin_amdgcn_global_load_lds(
        (const __attribute__((address_space(1))) uint32_t*)g,
        (__attribute__((address_space(3))) uint32_t*)lwb, 16, 0, 0);
#else
    *(uint4*)(lwb + lane*4) = *(const uint4*)g;
#endif
}

// ---------------- K0: ALL prep work fused ----------------
// blocks [0,2048): obs->f16 | [2048,2560): state->f16 | [2560,2944): Wh pack (MFMA v2 layout)
// [2944,3136): tr Wx | [3136,3152): tr W1 | [3152,3156): tr W1e | [3156,3172): tr W2
// Wh v2 layout: u32 idx = ((w*8+kk)*6+n)*256 + lane*4 + p
//   value = pair(Wh[k][col], Wh[k+1][col]), k = kk*32+(lane>>4)*8+2p,
//   col = (n>>1)*256 + w*32 + (n&1)*16 + (lane&15)   [r8/r11-verified fragment mapping]
__global__ __launch_bounds__(256)
void k_prep_all(const float* __restrict__ obs, const float* __restrict__ st,
                const float* __restrict__ Wh, const float* __restrict__ Wx,
                const float* __restrict__ W1, const float* __restrict__ W2,
                uint32_t* __restrict__ obs16, uint32_t* __restrict__ st16,
                uint32_t* __restrict__ WhM, uint32_t* __restrict__ WxT16,
                uint32_t* __restrict__ W1T16, uint32_t* __restrict__ W1eT16,
                uint32_t* __restrict__ W2T16)
{
    __shared__ float t_[64][65];
    int bid = blockIdx.x;
    int tid = threadIdx.x;
    if (bid < 2048) {
        int idx = bid*256 + tid;
        int r = idx >> 7, q = idx & 127;
        int a = q >> 3, f8 = (q & 7)*8;
        const float* p = obs + ((size_t)r*16 + a)*128 + f8;
        float4 v0 = *(const float4*)p, v1 = *(const float4*)(p+4);
        uint4 o; o.x=packh2(v0.x,v0.y); o.y=packh2(v0.z,v0.w);
        o.z=packh2(v1.x,v1.y); o.w=packh2(v1.z,v1.w);
        *(uint4*)(obs16 + (size_t)idx*4) = o;
    } else if (bid < 2560) {
        int idx = (bid-2048)*256 + tid;
        int r = idx >> 5, q = idx & 31;
        const float* p = st + (size_t)r*256 + q*8;
        float4 v0 = *(const float4*)p, v1 = *(const float4*)(p+4);
        uint4 o; o.x=packh2(v0.x,v0.y); o.y=packh2(v0.z,v0.w);
        o.z=packh2(v1.x,v1.y); o.w=packh2(v1.z,v1.w);
        *(uint4*)(st16 + (size_t)idx*4) = o;
    } else if (bid < 2944) {
        int g = (bid-2560)*256 + tid;       // 0..98303
        int p = g & 3;
        int lane = (g >> 2) & 63;
        int f = g >> 8;
        int n = f % 6;
        int g2 = f / 6;
        int kk = g2 & 7;
        int w = g2 >> 3;
        int k = kk*32 + (lane>>4)*8 + 2*p;
        int col = (n>>1)*256 + w*32 + (n&1)*16 + (lane&15);
        WhM[g] = packh2(Wh[(size_t)k*768 + col], Wh[(size_t)(k+1)*768 + col]);
    } else {
        const float* src; uint32_t* out; int N, Khalf, k0, n0;
        if (bid < 3136)      { int lin = bid-2944; src = Wx;          out = WxT16;  N = 768; Khalf = 512; k0 = (lin & 15)*64; n0 = (lin >> 4)*64; }
        else if (bid < 3152) { int lin = bid-3136; src = W1;          out = W1T16;  N = 256; Khalf = 128; k0 = (lin & 3)*64;  n0 = (lin >> 2)*64; }
        else if (bid < 3156) { int lin = bid-3152; src = W1 + 272*256; out = W1eT16; N = 256; Khalf = 32;  k0 = 0;             n0 = lin*64; }
        else                 { int lin = bid-3156; src = W2;          out = W2T16;  N = 256; Khalf = 128; k0 = (lin & 3)*64;  n0 = (lin >> 2)*64; }
#pragma unroll
        for (int rep = 0; rep < 4; ++rep) {
            int idx = rep*256 + tid;
            int r = idx >> 4, c4 = (idx & 15)*4;
            float4 v = *(const float4*)(src + (size_t)(k0+r)*N + n0 + c4);
            t_[r][c4] = v.x; t_[r][c4+1] = v.y; t_[r][c4+2] = v.z; t_[r][c4+3] = v.w;
        }
        __syncthreads();
#pragma unroll
        for (int rep = 0; rep < 8; ++rep) {
            int idx = rep*256 + tid;
            int nl = idx >> 5, kp = idx & 31;
            out[(size_t)(n0+nl)*Khalf + (k0>>1) + kp] = packh2(t_[kp*2][nl], t_[kp*2+1][nl]);
        }
    }
}

// ---------------- MFMA f16 GEMM body: C[M,N] = A16[M,K] @ BT16[N,K]^T + bias ----------------
template<int OUT16>
__device__ __forceinline__
void xg_body(uint32_t (*lds)[8192], int bid, int nwg,
             const uint32_t* __restrict__ A16, const uint32_t* __restrict__ BT16,
             const float* __restrict__ bias, float* __restrict__ Cp,
             int N, int K, int nTilesN)
{
    int qq = nwg >> 3;
    int logical = (bid & 7)*qq + (bid >> 3);
    int bm = logical / nTilesN, bn = logical % nTilesN;
    int m0 = bm*128, n0 = bn*128;
    int tid = threadIdx.x;
    int lane = tid & 63, wave = tid >> 6;
    int wr = wave >> 1, wc = wave & 1;
    int Ku = K >> 1;

    f32x4 acc[4][4];
#pragma unroll
    for (int i = 0; i < 4; ++i)
#pragma unroll
        for (int j = 0; j < 4; ++j) acc[i][j] = (f32x4){0.f,0.f,0.f,0.f};

    auto STAGE = [&](int buf, int k0) {
#pragma unroll
        for (int i = 0; i < 8; ++i) {
            int c = i*256 + tid;
            int cr = c & 1023;
            int row = cr >> 3, kq = cr & 7;
            const uint32_t* src;
            if (c < 1024) src = A16 + (size_t)(m0+row)*Ku + (k0>>1) + ((kq ^ (row&7))<<2);
            else          src = BT16 + (size_t)(n0+row)*Ku + (k0>>1) + ((kq ^ (row&7))<<2);
            gl_lds16(src, &lds[buf][(size_t)((i*256 + (wave<<6))<<2)], lane);
        }
    };

    STAGE(0, 0);
    __syncthreads();
    int NT = K >> 6;
    for (int t = 0; t < NT; ++t) {
        int cur = t & 1;
        if (t + 1 < NT) STAGE(cur ^ 1, (t+1) << 6);
        const uint32_t* Ab = &lds[cur][0];
        const uint32_t* Bb = &lds[cur][4096];
#pragma unroll
        for (int kk = 0; kk < 2; ++kk) {
            f16x8 af[4], bf[4];
#pragma unroll
            for (int im = 0; im < 4; ++im) {
                int row = wr*64 + im*16 + (lane & 15);
                int ck = (kk*4 + (lane >> 4)) ^ (row & 7);
                af[im] = *(const f16x8*)(Ab + row*32 + ck*4);
            }
#pragma unroll
            for (int in = 0; in < 4; ++in) {
                int row = wc*64 + in*16 + (lane & 15);
                int ck = (kk*4 + (lane >> 4)) ^ (row & 7);
                bf[in] = *(const f16x8*)(Bb + row*32 + ck*4);
            }
#pragma unroll
            for (int im = 0; im < 4; ++im)
#pragma unroll
                for (int in = 0; in < 4; ++in)
                    acc[im][in] = MFMA16(af[im], bf[in], acc[im][in]);
        }
        __syncthreads();
    }
#pragma unroll
    for (int im = 0; im < 4; ++im)
#pragma unroll
        for (int in = 0; in < 4; ++in) {
            int col = n0 + wc*64 + in*16 + (lane & 15);
            float bv = bias[col];
#pragma unroll
            for (int r = 0; r < 4; ++r) {
                int row = m0 + wr*64 + im*16 + (lane >> 4)*4 + r;
                float v = acc[im][in][r] + bv;
                if (OUT16) ((uint16_t*)Cp)[(size_t)row*N + col] =
                    __builtin_bit_cast(uint16_t, (_Float16)v);
                else Cp[(size_t)row*N + col] = v;
            }
        }
}

// ---------------- K1: both GEMMs in one launch ----------------
__global__ __launch_bounds__(256, 2)
void k_gemms(const uint32_t* __restrict__ obs16, const uint32_t* __restrict__ WxT16,
             const float* __restrict__ b_gru, float* __restrict__ XGout,
             const uint32_t* __restrict__ st16, const uint32_t* __restrict__ W1T16,
             const float* __restrict__ b1, float* __restrict__ S1)
{
    __shared__ __align__(16) uint32_t lds[2][8192];
    int bid = blockIdx.x;
    if (bid < 192) xg_body<1>(lds, bid, 192, obs16, WxT16, b_gru, XGout, 768, 1024, 6);
    else           xg_body<0>(lds, bid - 192, 64, st16, W1T16, b1, S1, 256, 256, 2);
}

// ---------------- K2: GRU scan via MFMA, W banks STREAMED from L2 (3-deep rotation) ----
// 2 WGs x 512 thr (16 chains/WG; grid MUST be 2). Tail/staging identical to r11 (verified).
// Live regs: 3 banks x 48 + 24 acc + ~25 misc ~ 193 <= 256 @ (512,2).
__global__ __launch_bounds__(512, 2)
void k_scan(const uint32_t* __restrict__ WhM, const uint16_t* __restrict__ XG16,
            float* __restrict__ h_all)
{
    __shared__ __align__(16) uint16_t hF[4096];        // 8 KB: h fragment buffer
    __shared__ __align__(16) uint16_t xgL[2][12288];   // 2 x 24 KB xg staging
    _Float16* hFh = (_Float16*)hF;
    const int tid = threadIdx.x;
    const int wave = tid >> 6, lane = tid & 63;
    const int bbase = blockIdx.x * 16;
    const int bt0 = (lane >> 4) * 4;
    const int un = lane & 15;

    ((uint4*)hF)[tid] = (uint4){0u,0u,0u,0u};   // zero 8KB

    // per-(wave,kk) contiguous 6-frag groups: uint4 idx = wave*3072 + kk*384 + n*64 + lane
    const uint4* wkb = (const uint4*)WhM + (size_t)wave*3072 + lane;

    // stage xg for step stp into xgL[buf]: 1536 16B-chunks (16 batches x 96)
    auto STAGE_XG = [&](int buf, int stp) {
        int stc = stp < TT ? stp : TT - 1;
#pragma unroll
        for (int it = 0; it < 3; ++it) {
            int c = it*512 + tid;
            int b = c / 96;
            int off = c - b*96;
            gl_lds16((const uint32_t*)(XG16 + ((size_t)(bbase + b)*TT + stc)*768 + off*8),
                     (uint32_t*)xgL + (size_t)buf*6144 + (size_t)((it*512 + (wave<<6))<<2),
                     lane);
        }
    };

    f32x4 hold0 = {0.f,0.f,0.f,0.f}, hold1 = {0.f,0.f,0.f,0.f};
    STAGE_XG(0, 0);
    __syncthreads();   // hF zeroed + xg(0) staged

    for (int st = 0; st < TT; ++st) {
        STAGE_XG((st + 1) & 1, st + 1);   // next step's xg; completes by barrier below
        f32x4 a0={0.f,0.f,0.f,0.f}, a1={0.f,0.f,0.f,0.f}, a2={0.f,0.f,0.f,0.f},
              a3={0.f,0.f,0.f,0.f}, a4={0.f,0.f,0.f,0.f}, a5={0.f,0.f,0.f,0.f};
        f16x8 A0,A1,A2,A3,A4,A5, B0,B1,B2,B3,B4,B5, C0,C1,C2,C3,C4,C5;
#define LDB(P, kk) { const uint4* wp_ = wkb + (kk)*384; \
        P##0 = *(const f16x8*)(wp_);       P##1 = *(const f16x8*)(wp_+64); \
        P##2 = *(const f16x8*)(wp_+128);   P##3 = *(const f16x8*)(wp_+192); \
        P##4 = *(const f16x8*)(wp_+256);   P##5 = *(const f16x8*)(wp_+320); }
#define MM(P, kk) { f16x8 af = *(const f16x8*)&hFh[((kk)*64 + lane)*8]; \
        a0 = MFMA16(af, P##0, a0); a1 = MFMA16(af, P##1, a1); \
        a2 = MFMA16(af, P##2, a2); a3 = MFMA16(af, P##3, a3); \
        a4 = MFMA16(af, P##4, a4); a5 = MFMA16(af, P##5, a5); }
        LDB(A,0) LDB(B,1) LDB(C,2)
        MM(A,0) LDB(A,3)
        MM(B,1) LDB(B,4)
        MM(C,2) LDB(C,5)
        MM(A,3) LDB(A,6)
        MM(B,4) LDB(B,7)
        MM(C,5)
        MM(A,6)
        MM(B,7)
#undef MM
#undef LDB
        __syncthreads();   // hF reads done; xg(st) staging complete
        const _Float16* xq = (const _Float16*)xgL[st & 1] + bt0*768 + wave*32 + un;
        float* hwp = h_all + ((size_t)(bbase + bt0)) * TT * 256 + (size_t)st*256 + wave*32 + un;
#define TAILR(s, r, AR, AZ, AN, HOLD) { \
        float XR = (float)xq[r*768 + 0*256 + s*16]; \
        float XZ = (float)xq[r*768 + 1*256 + s*16]; \
        float XN = (float)xq[r*768 + 2*256 + s*16]; \
        float R = sigm(XR + AR[r]); \
        float Z = sigm(XZ + AZ[r]); \
        float Nv = tanh_f(XN + R*AN[r]); \
        float hn = (1.f - Z)*Nv + Z*HOLD[r]; \
        HOLD[r] = hn; \
        hFh[(((s*2 + (un>>3))<<4) + wave*64 + bt0 + r)*8 + (un&7)] = (_Float16)hn; \
        hwp[(size_t)r*32768 + s*16] = hn; }
        TAILR(0,0,a0,a2,a4,hold0) TAILR(0,1,a0,a2,a4,hold0)
        TAILR(0,2,a0,a2,a4,hold0) TAILR(0,3,a0,a2,a4,hold0)
        TAILR(1,0,a1,a3,a5,hold1) TAILR(1,1,a1,a3,a5,hold1)
        TAILR(1,2,a1,a3,a5,hold1) TAILR(1,3,a1,a3,a5,hold1)
#undef TAILR
        __syncthreads();   // h(st) visible to all waves
    }
}

// ---------------- K4: hypergraph conv (unchanged) ----------------
__global__ __launch_bounds__(256)
void k_hyper(const float* __restrict__ h_all, const float* __restrict__ obs,
             const float* __restrict__ W_inc, const float* __restrict__ b_inc,
             const float* __restrict__ W_hg,
             float* __restrict__ graphs, uint32_t* __restrict__ emb_pk)
{
    __shared__ float hs[256];
    __shared__ float hm[128];
    __shared__ float rdv[16];
    __shared__ float rde[8];
    __shared__ float xs[16][64];
    __shared__ float msg[8][64];
    __shared__ float outs[16][64];
    int r = blockIdx.x;
    int t = threadIdx.x;
    hs[t] = h_all[(size_t)r*256 + t];
    __syncthreads();
    if (t < 128) {
        float a = b_inc[t];
#pragma unroll 8
        for (int k = 0; k < 256; ++k) a = fmaf(hs[k], W_inc[k*128 + t], a);
        float s = sigm(a);
        hm[t] = s;
        graphs[(size_t)r*128 + t] = s;
    }
    __syncthreads();
    if (t < 16) {
        float s = EPSV;
#pragma unroll
        for (int e = 0; e < 8; ++e) s += hm[t*8 + e];
        rdv[t] = 1.f/sqrtf(s);
    } else if (t >= 64 && t < 72) {
        int e = t - 64;
        float s = EPSV;
#pragma unroll
        for (int a2 = 0; a2 < 16; ++a2) s += hm[a2*8 + e];
        rde[e] = 1.f/s;
    }
    __syncthreads();
    {
        int aa = t >> 4, f4 = t & 15;
        float4 v = *(const float4*)(obs + (size_t)r*2048 + aa*128 + f4*4);
        float sc = rdv[aa];
        *(float4*)&xs[aa][f4*4] = make_float4(v.x*sc, v.y*sc, v.z*sc, v.w*sc);
    }
    __syncthreads();
#pragma unroll
    for (int rep = 0; rep < 2; ++rep) {
        int o = rep*256 + t;
        int e = o >> 6, f = o & 63;
        float s = 0.f;
#pragma unroll
        for (int a2 = 0; a2 < 16; ++a2) s = fmaf(hm[a2*8 + e], xs[a2][f], s);
        msg[e][f] = s * rde[e];
    }
    __syncthreads();
#pragma unroll
    for (int rep = 0; rep < 4; ++rep) {
        int o = rep*256 + t;
        int a2 = o >> 6, f = o & 63;
        float s = 0.f;
#pragma unroll
        for (int e = 0; e < 8; ++e) s = fmaf(hm[a2*8 + e], msg[e][f], s);
        outs[a2][f] = s * rdv[a2];
    }
    __syncthreads();
    {
        int aa = t >> 4, fo0 = (t & 15)*4;
        float s0=0,s1=0,s2=0,s3=0;
#pragma unroll 8
        for (int f = 0; f < 64; ++f) {
            float ov = outs[aa][f];
            float4 wv = *(const float4*)(W_hg + f*64 + fo0);
            s0 = fmaf(ov, wv.x, s0); s1 = fmaf(ov, wv.y, s1);
            s2 = fmaf(ov, wv.z, s2); s3 = fmaf(ov, wv.w, s3);
        }
        s0 = fmaxf(s0,0.f); s1 = fmaxf(s1,0.f); s2 = fmaxf(s2,0.f); s3 = fmaxf(s3,0.f);
        uint2 pk; pk.x = packh2(s0, s1); pk.y = packh2(s2, s3);
        *(uint2*)&emb_pk[((size_t)r*16 + aa)*32 + (t & 15)*2] = pk;
    }
}

// ---------------- K5: fused MLP head, MFMA; 128 rows/block, 8 waves ----------------
__global__ __launch_bounds__(512, 2)
void k_mlp(const uint32_t* __restrict__ emb_pk, const float* __restrict__ S1,
           const float* __restrict__ W1, const uint32_t* __restrict__ W1eT16,
           const uint32_t* __restrict__ W2T16,
           const float* __restrict__ b2, const float* __restrict__ W3,
           const float* __restrict__ b3, float* __restrict__ qout)
{
    __shared__ __align__(16) uint32_t x1s[16384];
    __shared__ __align__(16) uint32_t wbuf[2][8192];
    __shared__ float qpart[128][2];
    int tid = threadIdx.x;
    int lane = tid & 63, wave = tid >> 6;
    int wr = wave >> 1, wc = wave & 1;
    int rowbase = blockIdx.x * 128;

#pragma unroll
    for (int i = 0; i < 4; ++i) {
        int c = i*512 + tid;
        int row = c >> 3, kq = c & 7;
        gl_lds16(W1eT16 + (size_t)row*32 + ((kq ^ (row&7))<<2),
                 &wbuf[0][(size_t)((i*512 + (wave<<6))<<2)], lane);
    }
#pragma unroll
    for (int i = 0; i < 2; ++i) {
        int c = i*512 + tid;
        int row = c >> 3, kq = c & 7;
        gl_lds16(emb_pk + (size_t)(rowbase+row)*32 + ((kq ^ (row&7))<<2),
                 &wbuf[1][(size_t)((i*512 + (wave<<6))<<2)], lane);
    }
    f32x4 acc[2][8];
#pragma unroll
    for (int im = 0; im < 2; ++im)
#pragma unroll
        for (int in = 0; in < 8; ++in) {
            int col = wc*128 + in*16 + (lane & 15);
#pragma unroll
            for (int r = 0; r < 4; ++r) {
                int rl = wr*32 + im*16 + (lane >> 4)*4 + r;
                int grow = rowbase + rl;
                acc[im][in][r] = S1[(size_t)(grow >> 4)*256 + col]
                               + W1[(size_t)(256 + (grow & 15))*256 + col];
            }
        }
    __syncthreads();
#pragma unroll
    for (int kk = 0; kk < 2; ++kk) {
        f16x8 af[2], bf[8];
#pragma unroll
        for (int im = 0; im < 2; ++im) {
            int row = wr*32 + im*16 + (lane & 15);
            int ck = (kk*4 + (lane >> 4)) ^ (row & 7);
            af[im] = *(const f16x8*)(&wbuf[1][row*32 + ck*4]);
        }
#pragma unroll
        for (int in = 0; in < 8; ++in) {
            int n = wc*128 + in*16 + (lane & 15);
            int ck = (kk*4 + (lane >> 4)) ^ (n & 7);
            bf[in] = *(const f16x8*)(&wbuf[0][n*32 + ck*4]);
        }
#pragma unroll
        for (int im = 0; im < 2; ++im)
#pragma unroll
            for (int in = 0; in < 8; ++in)
                acc[im][in] = MFMA16(af[im], bf[in], acc[im][in]);
    }
#pragma unroll
    for (int im = 0; im < 2; ++im)
#pragma unroll
        for (int in = 0; in < 8; ++in) {
            int col = wc*128 + in*16 + (lane & 15);
            int chunk = col >> 3, pos = col & 7;
#pragma unroll
            for (int r = 0; r < 4; ++r) {
                int rl = wr*32 + im*16 + (lane >> 4)*4 + r;
                int swc = chunk ^ (rl & 7);
                *((_Float16*)x1s + rl*256 + swc*8 + pos) =
                    (_Float16)fmaxf(acc[im][in][r], 0.f);
                acc[im][in][r] = 0.f;
            }
        }
    __syncthreads();
    auto STAGE_W2 = [&](int buf, int kc) {
#pragma unroll
        for (int i = 0; i < 4; ++i) {
            int c = i*512 + tid;
            int row = c >> 3, kq = c & 7;
            gl_lds16(W2T16 + (size_t)row*128 + kc*32 + ((kq ^ (row&7))<<2),
                     &wbuf[buf][(size_t)((i*512 + (wave<<6))<<2)], lane);
        }
    };
    STAGE_W2(0, 0);
    __syncthreads();
    for (int kc = 0; kc < 4; ++kc) {
        int cur = kc & 1;
        if (kc + 1 < 4) STAGE_W2(cur ^ 1, kc + 1);
#pragma unroll
        for (int kk = 0; kk < 2; ++kk) {
            f16x8 af[2], bf[8];
#pragma unroll
            for (int im = 0; im < 2; ++im) {
                int row = wr*32 + im*16 + (lane & 15);
                int g = kc*8 + kk*4 + (lane >> 4);
                int ck = g ^ (row & 7);
                af[im] = *(const f16x8*)(&x1s[row*128 + ck*4]);
            }
#pragma unroll
            for (int in = 0; in < 8; ++in) {
                int n = wc*128 + in*16 + (lane & 15);
                int ck = (kk*4 + (lane >> 4)) ^ (n & 7);
                bf[in] = *(const f16x8*)(&wbuf[cur][n*32 + ck*4]);
            }
#pragma unroll
            for (int im = 0; im < 2; ++im)
#pragma unroll
                for (int in = 0; in < 8; ++in)
                    acc[im][in] = MFMA16(af[im], bf[in], acc[im][in]);
        }
        __syncthreads();
    }
    float w3v[8], b2v[8];
#pragma unroll
    for (int in = 0; in < 8; ++in) {
        int col = wc*128 + in*16 + (lane & 15);
        w3v[in] = W3[col]; b2v[in] = b2[col];
    }
#pragma unroll
    for (int im = 0; im < 2; ++im)
#pragma unroll
        for (int r = 0; r < 4; ++r) {
            float qp = 0.f;
#pragma unroll
            for (int in = 0; in < 8; ++in)
                qp = fmaf(fmaxf(acc[im][in][r] + b2v[in], 0.f), w3v[in], qp);
            qp += __shfl_xor(qp, 1);
            qp += __shfl_xor(qp, 2);
            qp += __shfl_xor(qp, 4);
            qp += __shfl_xor(qp, 8);
            if ((lane & 15) == 0)
                qpart[wr*32 + im*16 + (lane >> 4)*4 + r][wc] = qp;
        }
    __syncthreads();
    if (tid < 128)
        qout[rowbase + tid] = qpart[tid][0] + qpart[tid][1] + b3[0];
}

extern "C" void kernel_launch(void* const* d_in, const int* in_sizes, int n_in,
                              void* d_out, int out_size, void* d_ws, size_t ws_size,
                              hipStream_t stream)
{
    const float* state = (const float*)d_in[0];
    const float* obs   = (const float*)d_in[1];
    const float* Wx    = (const float*)d_in[2];
    const float* Wh    = (const float*)d_in[3];
    const float* b_gru = (const float*)d_in[4];
    const float* W_inc = (const float*)d_in[5];
    const float* b_inc = (const float*)d_in[6];
    const float* W_hg  = (const float*)d_in[7];
    const float* W1    = (const float*)d_in[8];
    const float* b1    = (const float*)d_in[9];
    const float* W2    = (const float*)d_in[10];
    const float* b2    = (const float*)d_in[11];
    const float* W3    = (const float*)d_in[12];
    const float* b3    = (const float*)d_in[13];
    float* qout   = (float*)d_out;
    float* graphs = (float*)d_out + NAR;

    float* base = (float*)d_ws;
    uint16_t* XG16   = (uint16_t*)base;                   // 4096*768 u16
    float* hall      = base + 1572864;                    // 1,048,576 f
    float* S1        = base + 2621440;                    // 1,048,576 f
    uint32_t* emb_pk = (uint32_t*)(base + 3670016);       // 2,097,152 u32
    uint32_t* WhM    = (uint32_t*)(base + 5767168);       //    98,304 u32
    uint32_t* obs16  = (uint32_t*)(base + 5865472);       // 2,097,152 u32
    uint32_t* st16   = (uint32_t*)(base + 7962624);       //   524,288 u32
    uint32_t* WxT16  = (uint32_t*)(base + 8486912);       //   393,216 u32
    uint32_t* W1T16  = (uint32_t*)(base + 8880128);       //    32,768 u32
    uint32_t* W1eT16 = (uint32_t*)(base + 8912896);       //     8,192 u32
    uint32_t* W2T16  = (uint32_t*)(base + 8921088);       //    32,768 u32

    hipLaunchKernelGGL(k_prep_all, dim3(3172), dim3(256), 0, stream,
                       obs, state, Wh, Wx, W1, W2,
                       obs16, st16, WhM, WxT16, W1T16, W1eT16, W2T16);
    hipLaunchKernelGGL(k_gemms, dim3(256), dim3(256), 0, stream,
                       obs16, WxT16, b_gru, (float*)XG16, st16, W1T16, b1, S1);
    hipLaunchKernelGGL(k_scan, dim3(2), dim3(512), 0, stream, WhM, XG16, hall);
    hipLaunchKernelGGL(k_hyper, dim3(4096), dim3(256), 0, stream,
                       hall, obs, W_inc, b_inc, W_hg, graphs, emb_pk);
    hipLaunchKernelGGL(k_mlp, dim3(512), dim3(512), 0, stream,
                       emb_pk, S1, W1, W1eT16, W2T16, b2, W3, b3, qout);
}

// Round 14
// 239.470 us; speedup vs baseline: 1.9961x; 1.9961x over previous
//
#include <hip/hip_runtime.h>
#include <hip/hip_bf16.h>
#include <stdint.h>

#define BSZ 32
#define TT 128
#define NAG 16
#define NROW 4096
#define NAR 65536
#define EPSV 1e-6f

typedef __attribute__((ext_vector_type(2))) _Float16 half2v;
typedef _Float16 f16x8 __attribute__((ext_vector_type(8)));
typedef float f32x4 __attribute__((ext_vector_type(4)));

#define MFMA16(a,b,c) __builtin_amdgcn_mfma_f32_16x16x32_f16(a,b,c,0,0,0)

__device__ __forceinline__ float dot2f(uint32_t a, uint32_t b, float c) {
#if __has_builtin(__builtin_amdgcn_fdot2)
    return __builtin_amdgcn_fdot2(__builtin_bit_cast(half2v, a),
                                  __builtin_bit_cast(half2v, b), c, false);
#else
    half2v ha = __builtin_bit_cast(half2v, a);
    half2v hb = __builtin_bit_cast(half2v, b);
    return c + (float)ha.x*(float)hb.x + (float)ha.y*(float)hb.y;
#endif
}

__device__ __forceinline__ uint32_t packh2(float a, float b) {
    union { half2v h; uint32_t u; } cu;
    cu.h.x = (_Float16)a; cu.h.y = (_Float16)b;
    return cu.u;
}

__device__ __forceinline__ float sigm(float x) { return 1.f/(1.f + __expf(-x)); }
__device__ __forceinline__ float tanh_f(float x) { return 1.f - 2.f/(__expf(2.f*x) + 1.f); }

// async 16B global->LDS; dest = wave-uniform base + lane*16 (linear)
__device__ __forceinline__ void gl_lds16(const uint32_t* g, uint32_t* lwb, int lane) {
#if __has_builtin(__builtin_amdgcn_global_load_lds)
    __builtin_amdgcn_global_load_lds(
        (const __attribute__((address_space(1))) uint32_t*)g,
        (__attribute__((address_space(3))) uint32_t*)lwb, 16, 0, 0);
#else
    *(uint4*)(lwb + lane*4) = *(const uint4*)g;
#endif
}

// ---------------- K0: ALL prep work fused (r12 version, r9 Wh layout) ----------------
// blocks [0,2048): obs->f16 | [2048,2560): state->f16 | [2560,2944): Wh pack (r9 layout)
// [2944,3136): tr Wx | [3136,3152): tr W1 | [3152,3156): tr W1e | [3156,3172): tr W2
__global__ __launch_bounds__(256)
void k_prep_all(const float* __restrict__ obs, const float* __restrict__ st,
                const float* __restrict__ Wh, const float* __restrict__ Wx,
                const float* __restrict__ W1, const float* __restrict__ W2,
                uint32_t* __restrict__ obs16, uint32_t* __restrict__ st16,
                uint32_t* __restrict__ WhP, uint32_t* __restrict__ WxT16,
                uint32_t* __restrict__ W1T16, uint32_t* __restrict__ W1eT16,
                uint32_t* __restrict__ W2T16)
{
    __shared__ float t_[64][65];
    int bid = blockIdx.x;
    int tid = threadIdx.x;
    if (bid < 2048) {
        int idx = bid*256 + tid;
        int r = idx >> 7, q = idx & 127;
        int a = q >> 3, f8 = (q & 7)*8;
        const float* p = obs + ((size_t)r*16 + a)*128 + f8;
        float4 v0 = *(const float4*)p, v1 = *(const float4*)(p+4);
        uint4 o; o.x=packh2(v0.x,v0.y); o.y=packh2(v0.z,v0.w);
        o.z=packh2(v1.x,v1.y); o.w=packh2(v1.z,v1.w);
        *(uint4*)(obs16 + (size_t)idx*4) = o;
    } else if (bid < 2560) {
        int idx = (bid-2048)*256 + tid;
        int r = idx >> 5, q = idx & 31;
        const float* p = st + (size_t)r*256 + q*8;
        float4 v0 = *(const float4*)p, v1 = *(const float4*)(p+4);
        uint4 o; o.x=packh2(v0.x,v0.y); o.y=packh2(v0.z,v0.w);
        o.z=packh2(v1.x,v1.y); o.w=packh2(v1.z,v1.w);
        *(uint4*)(st16 + (size_t)idx*4) = o;
    } else if (bid < 2944) {
        int g = (bid-2560)*256 + tid;       // 0..98303, r9 scan layout
        int kh = g / 49152;
        int r2 = g % 49152;
        int unit = r2 / 16384;
        int r3 = r2 % 16384;
        int gg = r3 >> 10;
        int r4 = r3 & 1023;
        int u = r4 >> 2;
        int j = r4 & 3;
        int k = kh*128 + 2*(gg*4 + j);
        int c = unit*256 + u;
        WhP[g] = packh2(Wh[(size_t)k*768 + c], Wh[(size_t)(k+1)*768 + c]);
    } else {
        const float* src; uint32_t* out; int N, Khalf, k0, n0;
        if (bid < 3136)      { int lin = bid-2944; src = Wx;          out = WxT16;  N = 768; Khalf = 512; k0 = (lin & 15)*64; n0 = (lin >> 4)*64; }
        else if (bid < 3152) { int lin = bid-3136; src = W1;          out = W1T16;  N = 256; Khalf = 128; k0 = (lin & 3)*64;  n0 = (lin >> 2)*64; }
        else if (bid < 3156) { int lin = bid-3152; src = W1 + 272*256; out = W1eT16; N = 256; Khalf = 32;  k0 = 0;             n0 = lin*64; }
        else                 { int lin = bid-3156; src = W2;          out = W2T16;  N = 256; Khalf = 128; k0 = (lin & 3)*64;  n0 = (lin >> 2)*64; }
#pragma unroll
        for (int rep = 0; rep < 4; ++rep) {
            int idx = rep*256 + tid;
            int r = idx >> 4, c4 = (idx & 15)*4;
            float4 v = *(const float4*)(src + (size_t)(k0+r)*N + n0 + c4);
            t_[r][c4] = v.x; t_[r][c4+1] = v.y; t_[r][c4+2] = v.z; t_[r][c4+3] = v.w;
        }
        __syncthreads();
#pragma unroll
        for (int rep = 0; rep < 8; ++rep) {
            int idx = rep*256 + tid;
            int nl = idx >> 5, kp = idx & 31;
            out[(size_t)(n0+nl)*Khalf + (k0>>1) + kp] = packh2(t_[kp*2][nl], t_[kp*2+1][nl]);
        }
    }
}

// ---------------- MFMA f16 GEMM body (unchanged) ----------------
template<int OUT16>
__device__ __forceinline__
void xg_body(uint32_t (*lds)[8192], int bid, int nwg,
             const uint32_t* __restrict__ A16, const uint32_t* __restrict__ BT16,
             const float* __restrict__ bias, float* __restrict__ Cp,
             int N, int K, int nTilesN)
{
    int qq = nwg >> 3;
    int logical = (bid & 7)*qq + (bid >> 3);
    int bm = logical / nTilesN, bn = logical % nTilesN;
    int m0 = bm*128, n0 = bn*128;
    int tid = threadIdx.x;
    int lane = tid & 63, wave = tid >> 6;
    int wr = wave >> 1, wc = wave & 1;
    int Ku = K >> 1;

    f32x4 acc[4][4];
#pragma unroll
    for (int i = 0; i < 4; ++i)
#pragma unroll
        for (int j = 0; j < 4; ++j) acc[i][j] = (f32x4){0.f,0.f,0.f,0.f};

    auto STAGE = [&](int buf, int k0) {
#pragma unroll
        for (int i = 0; i < 8; ++i) {
            int c = i*256 + tid;
            int cr = c & 1023;
            int row = cr >> 3, kq = cr & 7;
            const uint32_t* src;
            if (c < 1024) src = A16 + (size_t)(m0+row)*Ku + (k0>>1) + ((kq ^ (row&7))<<2);
            else          src = BT16 + (size_t)(n0+row)*Ku + (k0>>1) + ((kq ^ (row&7))<<2);
            gl_lds16(src, &lds[buf][(size_t)((i*256 + (wave<<6))<<2)], lane);
        }
    };

    STAGE(0, 0);
    __syncthreads();
    int NT = K >> 6;
    for (int t = 0; t < NT; ++t) {
        int cur = t & 1;
        if (t + 1 < NT) STAGE(cur ^ 1, (t+1) << 6);
        const uint32_t* Ab = &lds[cur][0];
        const uint32_t* Bb = &lds[cur][4096];
#pragma unroll
        for (int kk = 0; kk < 2; ++kk) {
            f16x8 af[4], bf[4];
#pragma unroll
            for (int im = 0; im < 4; ++im) {
                int row = wr*64 + im*16 + (lane & 15);
                int ck = (kk*4 + (lane >> 4)) ^ (row & 7);
                af[im] = *(const f16x8*)(Ab + row*32 + ck*4);
            }
#pragma unroll
            for (int in = 0; in < 4; ++in) {
                int row = wc*64 + in*16 + (lane & 15);
                int ck = (kk*4 + (lane >> 4)) ^ (row & 7);
                bf[in] = *(const f16x8*)(Bb + row*32 + ck*4);
            }
#pragma unroll
            for (int im = 0; im < 4; ++im)
#pragma unroll
                for (int in = 0; in < 4; ++in)
                    acc[im][in] = MFMA16(af[im], bf[in], acc[im][in]);
        }
        __syncthreads();
    }
#pragma unroll
    for (int im = 0; im < 4; ++im)
#pragma unroll
        for (int in = 0; in < 4; ++in) {
            int col = n0 + wc*64 + in*16 + (lane & 15);
            float bv = bias[col];
#pragma unroll
            for (int r = 0; r < 4; ++r) {
                int row = m0 + wr*64 + im*16 + (lane >> 4)*4 + r;
                float v = acc[im][in][r] + bv;
                if (OUT16) ((uint16_t*)Cp)[(size_t)row*N + col] =
                    __builtin_bit_cast(uint16_t, (_Float16)v);
                else Cp[(size_t)row*N + col] = v;
            }
        }
}

// ---------------- K1: both GEMMs in one launch ----------------
__global__ __launch_bounds__(256, 2)
void k_gemms(const uint32_t* __restrict__ obs16, const uint32_t* __restrict__ WxT16,
             const float* __restrict__ b_gru, float* __restrict__ XGout,
             const uint32_t* __restrict__ st16, const uint32_t* __restrict__ W1T16,
             const float* __restrict__ b1, float* __restrict__ S1)
{
    __shared__ __align__(16) uint32_t lds[2][8192];
    int bid = blockIdx.x;
    if (bid < 192) xg_body<1>(lds, bid, 192, obs16, WxT16, b_gru, XGout, 768, 1024, 6);
    else           xg_body<0>(lds, bid - 192, 64, st16, W1T16, b1, S1, 256, 256, 2);
}

// ---------------- K2: GRU scan — r9/r12 version (proven 147 us) ----------------
__global__ __launch_bounds__(512, 2)
void k_scan(const uint32_t* __restrict__ WhP, const uint16_t* __restrict__ XG16,
            float* __restrict__ h_all)
{
    __shared__ float psum[2*768];
    __shared__ uint32_t h16s[128];
    const int t = threadIdx.x;
    const int kh = t >> 8;
    const int u  = t & 255;
    const uint4* wp = (const uint4*)WhP + (size_t)kh*12288 + u;
    if (t < 128) h16s[t] = 0u;
    float hreg = 0.f;
    const _Float16* xp = (const _Float16*)XG16 + (size_t)blockIdx.x*TT*768 + u;
    float* hp = h_all + (size_t)blockIdx.x*TT*256 + u;
    float xgr = 0.f, xgz = 0.f, xgn = 0.f;
    if (t < 256) { xgr = (float)xp[0]; xgz = (float)xp[256]; xgn = (float)xp[512]; }
    xp += 768;
    __syncthreads();

    uint4 Ar0,Ar1,Ar2,Ar3, Az0,Az1,Az2,Az3, An0,An1,An2,An3;
    uint4 Br0,Br1,Br2,Br3, Bz0,Bz1,Bz2,Bz3, Bn0,Bn1,Bn2,Bn3;

#define LDBANK(P, g0) \
    P##r0 = wp[(g0+0)*256]; P##r1 = wp[(g0+1)*256]; \
    P##r2 = wp[(g0+2)*256]; P##r3 = wp[(g0+3)*256]; \
    P##z0 = wp[4096+(g0+0)*256]; P##z1 = wp[4096+(g0+1)*256]; \
    P##z2 = wp[4096+(g0+2)*256]; P##z3 = wp[4096+(g0+3)*256]; \
    P##n0 = wp[8192+(g0+0)*256]; P##n1 = wp[8192+(g0+1)*256]; \
    P##n2 = wp[8192+(g0+2)*256]; P##n3 = wp[8192+(g0+3)*256];

#define DOTG(HV, WR, WZ, WN) { uint4 hv_ = (HV); \
    a00=dot2f(hv_.x,WR.x,a00); a01=dot2f(hv_.y,WR.y,a01); \
    a00=dot2f(hv_.z,WR.z,a00); a01=dot2f(hv_.w,WR.w,a01); \
    a10=dot2f(hv_.x,WZ.x,a10); a11=dot2f(hv_.y,WZ.y,a11); \
    a10=dot2f(hv_.z,WZ.z,a10); a11=dot2f(hv_.w,WZ.w,a11); \
    a20=dot2f(hv_.x,WN.x,a20); a21=dot2f(hv_.y,WN.y,a21); \
    a20=dot2f(hv_.z,WN.z,a20); a21=dot2f(hv_.w,WN.w,a21); }

#define DOTBANK(P, g0) \
    DOTG(hq[g0+0], P##r0, P##z0, P##n0) \
    DOTG(hq[g0+1], P##r1, P##z1, P##n1) \
    DOTG(hq[g0+2], P##r2, P##z2, P##n2) \
    DOTG(hq[g0+3], P##r3, P##z3, P##n3)

    for (int st = 0; st < TT; ++st) {
        float nr = 0.f, nz = 0.f, nn = 0.f;
        if (t < 256) { nr = (float)xp[0]; nz = (float)xp[256]; nn = (float)xp[512]; }
        xp += 768;
        float a00=0.f,a01=0.f,a10=0.f,a11=0.f,a20=0.f,a21=0.f;
        const uint4* hq = (const uint4*)&h16s[kh*64];
        LDBANK(A, 0)
        LDBANK(B, 4)
        DOTBANK(A, 0)
        LDBANK(A, 8)
        DOTBANK(B, 4)
        LDBANK(B, 12)
        DOTBANK(A, 8)
        DOTBANK(B, 12)
        psum[kh*768 + u]       = a00 + a01;
        psum[kh*768 + 256 + u] = a10 + a11;
        psum[kh*768 + 512 + u] = a20 + a21;
        __syncthreads();
        if (t < 256) {
            float hr = psum[u]       + psum[768 + u];
            float hz = psum[256 + u] + psum[768 + 256 + u];
            float hn = psum[512 + u] + psum[768 + 512 + u];
            float rg = sigm(xgr + hr);
            float zg = sigm(xgz + hz);
            float ng = tanh_f(xgn + rg*hn);
            float hnew = (1.f - zg)*ng + zg*hreg;
            hreg = hnew;
            union { _Float16 h; uint16_t v; } cu; cu.h = (_Float16)hnew;
            ((uint16_t*)h16s)[u] = cu.v;
            *hp = hnew;
        }
        hp += 256;
        __syncthreads();
        xgr = nr; xgz = nz; xgn = nn;
    }
#undef DOTBANK
#undef DOTG
#undef LDBANK
}

// ---------------- K4: hypergraph conv, 8 rows/block (W_inc reused across rows) ----------
__global__ __launch_bounds__(256)
void k_hyper(const float* __restrict__ h_all, const float* __restrict__ obs,
             const float* __restrict__ W_inc, const float* __restrict__ b_inc,
             const float* __restrict__ W_hg,
             float* __restrict__ graphs, uint32_t* __restrict__ emb_pk)
{
    __shared__ float hs8[8][256];
    __shared__ float hm8[8][128];
    __shared__ float rdv8[8][16];
    __shared__ float rde8[8][8];
    __shared__ float xs[16][64];
    __shared__ float msg[8][64];
    __shared__ float outs[16][64];
    int r0 = blockIdx.x * 8;
    int t = threadIdx.x;
#pragma unroll
    for (int g = 0; g < 8; ++g)
        hs8[g][t] = h_all[(size_t)(r0+g)*256 + t];
    __syncthreads();
    // phase B: Hm for 8 rows; thread (pr=t>>7, col=t&127) handles rows pr*4..pr*4+3
    {
        int col = t & 127, pr = t >> 7;
        float bi = b_inc[col];
        float a0 = bi, a1 = bi, a2 = bi, a3 = bi;
        const float* hb0 = hs8[pr*4+0];
        const float* hb1 = hs8[pr*4+1];
        const float* hb2 = hs8[pr*4+2];
        const float* hb3 = hs8[pr*4+3];
#pragma unroll 8
        for (int k = 0; k < 256; ++k) {
            float w = W_inc[k*128 + col];
            a0 = fmaf(hb0[k], w, a0);
            a1 = fmaf(hb1[k], w, a1);
            a2 = fmaf(hb2[k], w, a2);
            a3 = fmaf(hb3[k], w, a3);
        }
        float s0 = sigm(a0), s1 = sigm(a1), s2 = sigm(a2), s3 = sigm(a3);
        hm8[pr*4+0][col] = s0; hm8[pr*4+1][col] = s1;
        hm8[pr*4+2][col] = s2; hm8[pr*4+3][col] = s3;
        graphs[(size_t)(r0+pr*4+0)*128 + col] = s0;
        graphs[(size_t)(r0+pr*4+1)*128 + col] = s1;
        graphs[(size_t)(r0+pr*4+2)*128 + col] = s2;
        graphs[(size_t)(r0+pr*4+3)*128 + col] = s3;
    }
    __syncthreads();
    // degrees: t<128 -> rdv (g=t>>4, a=t&15); t in [128,192) -> rde (g=(t-128)>>3, e=t&7)
    if (t < 128) {
        int g = t >> 4, a = t & 15;
        float s = EPSV;
#pragma unroll
        for (int e = 0; e < 8; ++e) s += hm8[g][a*8 + e];
        rdv8[g][a] = 1.f/sqrtf(s);
    } else if (t < 192) {
        int u2 = t - 128;
        int g = u2 >> 3, e = u2 & 7;
        float s = EPSV;
#pragma unroll
        for (int a2 = 0; a2 < 16; ++a2) s += hm8[g][a2*8 + e];
        rde8[g][e] = 1.f/s;
    }
    __syncthreads();
    for (int g = 0; g < 8; ++g) {
        int r = r0 + g;
        {
            int aa = t >> 4, f4 = t & 15;
            float4 v = *(const float4*)(obs + (size_t)r*2048 + aa*128 + f4*4);
            float sc = rdv8[g][aa];
            *(float4*)&xs[aa][f4*4] = make_float4(v.x*sc, v.y*sc, v.z*sc, v.w*sc);
        }
        __syncthreads();
#pragma unroll
        for (int rep = 0; rep < 2; ++rep) {
            int o = rep*256 + t;
            int e = o >> 6, f = o & 63;
            float s = 0.f;
#pragma unroll
            for (int a2 = 0; a2 < 16; ++a2) s = fmaf(hm8[g][a2*8 + e], xs[a2][f], s);
            msg[e][f] = s * rde8[g][e];
        }
        __syncthreads();
#pragma unroll
        for (int rep = 0; rep < 4; ++rep) {
            int o = rep*256 + t;
            int a2 = o >> 6, f = o & 63;
            float s = 0.f;
#pragma unroll
            for (int e = 0; e < 8; ++e) s = fmaf(hm8[g][a2*8 + e], msg[e][f], s);
            outs[a2][f] = s * rdv8[g][a2];
        }
        __syncthreads();
        {
            int aa = t >> 4, fo0 = (t & 15)*4;
            float s0=0,s1=0,s2=0,s3=0;
#pragma unroll 8
            for (int f = 0; f < 64; ++f) {
                float ov = outs[aa][f];
                float4 wv = *(const float4*)(W_hg + f*64 + fo0);
                s0 = fmaf(ov, wv.x, s0); s1 = fmaf(ov, wv.y, s1);
                s2 = fmaf(ov, wv.z, s2); s3 = fmaf(ov, wv.w, s3);
            }
            s0 = fmaxf(s0,0.f); s1 = fmaxf(s1,0.f); s2 = fmaxf(s2,0.f); s3 = fmaxf(s3,0.f);
            uint2 pk; pk.x = packh2(s0, s1); pk.y = packh2(s2, s3);
            *(uint2*)&emb_pk[((size_t)r*16 + aa)*32 + (t & 15)*2] = pk;
        }
        __syncthreads();
    }
}

// ---------------- K5: fused MLP head (unchanged) ----------------
__global__ __launch_bounds__(512, 2)
void k_mlp(const uint32_t* __restrict__ emb_pk, const float* __restrict__ S1,
           const float* __restrict__ W1, const uint32_t* __restrict__ W1eT16,
           const uint32_t* __restrict__ W2T16,
           const float* __restrict__ b2, const float* __restrict__ W3,
           const float* __restrict__ b3, float* __restrict__ qout)
{
    __shared__ __align__(16) uint32_t x1s[16384];
    __shared__ __align__(16) uint32_t wbuf[2][8192];
    __shared__ float qpart[128][2];
    int tid = threadIdx.x;
    int lane = tid & 63, wave = tid >> 6;
    int wr = wave >> 1, wc = wave & 1;
    int rowbase = blockIdx.x * 128;

#pragma unroll
    for (int i = 0; i < 4; ++i) {
        int c = i*512 + tid;
        int row = c >> 3, kq = c & 7;
        gl_lds16(W1eT16 + (size_t)row*32 + ((kq ^ (row&7))<<2),
                 &wbuf[0][(size_t)((i*512 + (wave<<6))<<2)], lane);
    }
#pragma unroll
    for (int i = 0; i < 2; ++i) {
        int c = i*512 + tid;
        int row = c >> 3, kq = c & 7;
        gl_lds16(emb_pk + (size_t)(rowbase+row)*32 + ((kq ^ (row&7))<<2),
                 &wbuf[1][(size_t)((i*512 + (wave<<6))<<2)], lane);
    }
    f32x4 acc[2][8];
#pragma unroll
    for (int im = 0; im < 2; ++im)
#pragma unroll
        for (int in = 0; in < 8; ++in) {
            int col = wc*128 + in*16 + (lane & 15);
#pragma unroll
            for (int r = 0; r < 4; ++r) {
                int rl = wr*32 + im*16 + (lane >> 4)*4 + r;
                int grow = rowbase + rl;
                acc[im][in][r] = S1[(size_t)(grow >> 4)*256 + col]
                               + W1[(size_t)(256 + (grow & 15))*256 + col];
            }
        }
    __syncthreads();
#pragma unroll
    for (int kk = 0; kk < 2; ++kk) {
        f16x8 af[2], bf[8];
#pragma unroll
        for (int im = 0; im < 2; ++im) {
            int row = wr*32 + im*16 + (lane & 15);
            int ck = (kk*4 + (lane >> 4)) ^ (row & 7);
            af[im] = *(const f16x8*)(&wbuf[1][row*32 + ck*4]);
        }
#pragma unroll
        for (int in = 0; in < 8; ++in) {
            int n = wc*128 + in*16 + (lane & 15);
            int ck = (kk*4 + (lane >> 4)) ^ (n & 7);
            bf[in] = *(const f16x8*)(&wbuf[0][n*32 + ck*4]);
        }
#pragma unroll
        for (int im = 0; im < 2; ++im)
#pragma unroll
            for (int in = 0; in < 8; ++in)
                acc[im][in] = MFMA16(af[im], bf[in], acc[im][in]);
    }
#pragma unroll
    for (int im = 0; im < 2; ++im)
#pragma unroll
        for (int in = 0; in < 8; ++in) {
            int col = wc*128 + in*16 + (lane & 15);
            int chunk = col >> 3, pos = col & 7;
#pragma unroll
            for (int r = 0; r < 4; ++r) {
                int rl = wr*32 + im*16 + (lane >> 4)*4 + r;
                int swc = chunk ^ (rl & 7);
                *((_Float16*)x1s + rl*256 + swc*8 + pos) =
                    (_Float16)fmaxf(acc[im][in][r], 0.f);
                acc[im][in][r] = 0.f;
            }
        }
    __syncthreads();
    auto STAGE_W2 = [&](int buf, int kc) {
#pragma unroll
        for (int i = 0; i < 4; ++i) {
            int c = i*512 + tid;
            int row = c >> 3, kq = c & 7;
            gl_lds16(W2T16 + (size_t)row*128 + kc*32 + ((kq ^ (row&7))<<2),
                     &wbuf[buf][(size_t)((i*512 + (wave<<6))<<2)], lane);
        }
    };
    STAGE_W2(0, 0);
    __syncthreads();
    for (int kc = 0; kc < 4; ++kc) {
        int cur = kc & 1;
        if (kc + 1 < 4) STAGE_W2(cur ^ 1, kc + 1);
#pragma unroll
        for (int kk = 0; kk < 2; ++kk) {
            f16x8 af[2], bf[8];
#pragma unroll
            for (int im = 0; im < 2; ++im) {
                int row = wr*32 + im*16 + (lane & 15);
                int g = kc*8 + kk*4 + (lane >> 4);
                int ck = g ^ (row & 7);
                af[im] = *(const f16x8*)(&x1s[row*128 + ck*4]);
            }
#pragma unroll
            for (int in = 0; in < 8; ++in) {
                int n = wc*128 + in*16 + (lane & 15);
                int ck = (kk*4 + (lane >> 4)) ^ (n & 7);
                bf[in] = *(const f16x8*)(&wbuf[cur][n*32 + ck*4]);
            }
#pragma unroll
            for (int im = 0; im < 2; ++im)
#pragma unroll
                for (int in = 0; in < 8; ++in)
                    acc[im][in] = MFMA16(af[im], bf[in], acc[im][in]);
        }
        __syncthreads();
    }
    float w3v[8], b2v[8];
#pragma unroll
    for (int in = 0; in < 8; ++in) {
        int col = wc*128 + in*16 + (lane & 15);
        w3v[in] = W3[col]; b2v[in] = b2[col];
    }
#pragma unroll
    for (int im = 0; im < 2; ++im)
#pragma unroll
        for (int r = 0; r < 4; ++r) {
            float qp = 0.f;
#pragma unroll
            for (int in = 0; in < 8; ++in)
                qp = fmaf(fmaxf(acc[im][in][r] + b2v[in], 0.f), w3v[in], qp);
            qp += __shfl_xor(qp, 1);
            qp += __shfl_xor(qp, 2);
            qp += __shfl_xor(qp, 4);
            qp += __shfl_xor(qp, 8);
            if ((lane & 15) == 0)
                qpart[wr*32 + im*16 + (lane >> 4)*4 + r][wc] = qp;
        }
    __syncthreads();
    if (tid < 128)
        qout[rowbase + tid] = qpart[tid][0] + qpart[tid][1] + b3[0];
}

extern "C" void kernel_launch(void* const* d_in, const int* in_sizes, int n_in,
                              void* d_out, int out_size, void* d_ws, size_t ws_size,
                              hipStream_t stream)
{
    const float* state = (const float*)d_in[0];
    const float* obs   = (const float*)d_in[1];
    const float* Wx    = (const float*)d_in[2];
    const float* Wh    = (const float*)d_in[3];
    const float* b_gru = (const float*)d_in[4];
    const float* W_inc = (const float*)d_in[5];
    const float* b_inc = (const float*)d_in[6];
    const float* W_hg  = (const float*)d_in[7];
    const float* W1    = (const float*)d_in[8];
    const float* b1    = (const float*)d_in[9];
    const float* W2    = (const float*)d_in[10];
    const float* b2    = (const float*)d_in[11];
    const float* W3    = (const float*)d_in[12];
    const float* b3    = (const float*)d_in[13];
    float* qout   = (float*)d_out;
    float* graphs = (float*)d_out + NAR;

    float* base = (float*)d_ws;
    uint16_t* XG16   = (uint16_t*)base;                   // 4096*768 u16
    float* hall      = base + 1572864;                    // 1,048,576 f
    float* S1        = base + 2621440;                    // 1,048,576 f
    uint32_t* emb_pk = (uint32_t*)(base + 3670016);       // 2,097,152 u32
    uint32_t* WhP    = (uint32_t*)(base + 5767168);       //    98,304 u32
    uint32_t* obs16  = (uint32_t*)(base + 5865472);       // 2,097,152 u32
    uint32_t* st16   = (uint32_t*)(base + 7962624);       //   524,288 u32
    uint32_t* WxT16  = (uint32_t*)(base + 8486912);       //   393,216 u32
    uint32_t* W1T16  = (uint32_t*)(base + 8880128);       //    32,768 u32
    uint32_t* W1eT16 = (uint32_t*)(base + 8912896);       //     8,192 u32
    uint32_t* W2T16  = (uint32_t*)(base + 8921088);       //    32,768 u32

    hipLaunchKernelGGL(k_prep_all, dim3(3172), dim3(256), 0, stream,
                       obs, state, Wh, Wx, W1, W2,
                       obs16, st16, WhP, WxT16, W1T16, W1eT16, W2T16);
    hipLaunchKernelGGL(k_gemms, dim3(256), dim3(256), 0, stream,
                       obs16, WxT16, b_gru, (float*)XG16, st16, W1T16, b1, S1);
    hipLaunchKernelGGL(k_scan, dim3(32), dim3(512), 0, stream, WhP, XG16, hall);
    hipLaunchKernelGGL(k_hyper, dim3(512), dim3(256), 0, stream,
                       hall, obs, W_inc, b_inc, W_hg, graphs, emb_pk);
    hipLaunchKernelGGL(k_mlp, dim3(512), dim3(512), 0, stream,
                       emb_pk, S1, W1, W1eT16, W2T16, b2, W3, b3, qout);
}